// Round 7
// baseline (475.638 us; speedup 1.0000x reference)
//
#include <hip/hip_runtime.h>
#include <hip/hip_bf16.h>
#include <math.h>

// Problem constants
#define D_MODEL 768
#define D_FF    3072
#define N_HEAD  12
#define HEAD_D  64
#define BATCH   2
#define SEQ     2048
#define QKV_LD  2304

typedef __attribute__((ext_vector_type(8))) short short8;            // 8 bf16 (4 VGPRs)
typedef __attribute__((ext_vector_type(8))) unsigned short ushort8;  // 16B staging
typedef __attribute__((ext_vector_type(4))) float f32x4;             // MFMA C/D frag

__device__ inline unsigned short f2bf(float f) {
    union { __hip_bfloat16 b; unsigned short u; } cv;
    cv.b = __float2bfloat16(f);
    return cv.u;
}

__device__ inline float bf2f(unsigned short u) {
    union { unsigned int i; float f; } cv;
    cv.i = ((unsigned int)u) << 16;
    return cv.f;
}

// ---------------- fused fp32->bf16 conversions + bias pack -------------------------
__global__ __launch_bounds__(256) void conv_fused(
    const float* __restrict__ x,
    const float* __restrict__ Wq, const float* __restrict__ Wk,
    const float* __restrict__ Wv, const float* __restrict__ Wp,
    const float* __restrict__ W1, const float* __restrict__ W2,
    const float* __restrict__ bq, const float* __restrict__ bk,
    const float* __restrict__ bv,
    unsigned short* __restrict__ xb, unsigned short* __restrict__ wqkvb,
    unsigned short* __restrict__ wpb, unsigned short* __restrict__ w1b,
    unsigned short* __restrict__ w2b, float* __restrict__ bqkv)
{
    int bid = blockIdx.x;
    const float* src; unsigned short* dst; int base;
    if      (bid < 3072) { src = x;  dst = xb;              base = bid;        }
    else if (bid < 3648) { src = Wq; dst = wqkvb;           base = bid - 3072; }
    else if (bid < 4224) { src = Wk; dst = wqkvb + 589824;  base = bid - 3648; }
    else if (bid < 4800) { src = Wv; dst = wqkvb + 1179648; base = bid - 4224; }
    else if (bid < 5376) { src = Wp; dst = wpb;             base = bid - 4800; }
    else if (bid < 7680) { src = W1; dst = w1b;             base = bid - 5376; }
    else if (bid < 9984) { src = W2; dst = w2b;             base = bid - 7680; }
    else {
        for (int j = threadIdx.x; j < QKV_LD; j += 256)
            bqkv[j] = (j < 768) ? bq[j] : (j < 1536) ? bk[j - 768] : bv[j - 1536];
        return;
    }
    int i = (base * 256 + threadIdx.x) * 4;
    float4 v = *(const float4*)(src + i);
    ushort4 o4;
    o4.x = f2bf(v.x); o4.y = f2bf(v.y); o4.z = f2bf(v.z); o4.w = f2bf(v.w);
    *(ushort4*)(dst + i) = o4;
}

// ---------------- bf16 MFMA GEMM, BK=64 register-prefetch pipeline -----------------
// C[m,n] = sum_k A[m,k]*W[n,k]; A:[M,K] bf16, W:[N,K] bf16 (NT).
// K-loop: global loads for tile k+1 -> VGPRs issued BEFORE computing tile k from
// LDS, so the vmcnt wait sits after the compute phase (latency hidden), then
// ds_write_b128 stages them (padded stride 72 shorts: b128 reads at conflict floor).
// gridDim.z = K-splits; z==0 does the epilogue, z>0 writes raw f32 partial to pacc.
// mode 0: outf = acc + bias
// mode 1: outf = acc + bias + bf16(resb)
// mode 2: outb = bf16(gelu_exact(acc + bias))   (do not split-K)
// mode 3: outb = bf16(acc + bias)
#define GSTR 72   // LDS row stride in shorts (144B: 16B-aligned, non-pow2 banks)

__global__ __launch_bounds__(256) void gemm_bf16(
    const unsigned short* __restrict__ A, int lda,
    const unsigned short* __restrict__ W, int ldw,
    const float* __restrict__ bias,
    const unsigned short* __restrict__ resb, int ldr,
    float* __restrict__ outf, unsigned short* __restrict__ outb,
    float* __restrict__ pacc, int ldo,
    int M, int N, int K, int mode)
{
    __shared__ unsigned short As[128 * GSTR];
    __shared__ unsigned short Bs[128 * GSTR];

    const int t    = threadIdx.x;
    const int lane = t & 63;
    const int wv   = t >> 6;
    const int wm   = wv >> 1;
    const int wn   = wv & 1;
    const int bm   = blockIdx.y * 128;
    const int bn   = blockIdx.x * 128;
    const int kz   = blockIdx.z;
    const int Kc   = K / gridDim.z;

    const int qd   = lane >> 4;
    const int l16  = lane & 15;

    f32x4 acc[4][4];
    #pragma unroll
    for (int i = 0; i < 4; i++)
        #pragma unroll
        for (int j = 0; j < 4; j++)
            acc[i][j] = (f32x4){0.f, 0.f, 0.f, 0.f};

    // staging map: f = t + i*256 -> row f>>3 (0..127), 16B seg (f&7)*8 shorts
    int rows[4], segs[4];
    #pragma unroll
    for (int i = 0; i < 4; i++) {
        int f = t + i * 256;
        rows[i] = f >> 3;
        segs[i] = (f & 7) * 8;
    }

    const int kbeg = kz * Kc, kend = kbeg + Kc;
    ushort8 ra[4], rb[4];

    // prologue: tile 0 -> regs -> LDS
    #pragma unroll
    for (int i = 0; i < 4; i++) {
        ra[i] = *(const ushort8*)(A + (size_t)(bm + rows[i]) * lda + kbeg + segs[i]);
        rb[i] = *(const ushort8*)(W + (size_t)(bn + rows[i]) * ldw + kbeg + segs[i]);
    }
    #pragma unroll
    for (int i = 0; i < 4; i++) {
        *(ushort8*)(As + rows[i] * GSTR + segs[i]) = ra[i];
        *(ushort8*)(Bs + rows[i] * GSTR + segs[i]) = rb[i];
    }
    __syncthreads();

    for (int k0 = kbeg; k0 < kend; k0 += 64) {
        const bool more = (k0 + 64 < kend);
        if (more) {
            #pragma unroll
            for (int i = 0; i < 4; i++) {
                ra[i] = *(const ushort8*)(A + (size_t)(bm + rows[i]) * lda + (k0 + 64) + segs[i]);
                rb[i] = *(const ushort8*)(W + (size_t)(bn + rows[i]) * ldw + (k0 + 64) + segs[i]);
            }
        }
        // compute current tile from LDS (2 k-chunks of 32)
        #pragma unroll
        for (int c = 0; c < 2; c++) {
            short8 af[4], bf[4];
            #pragma unroll
            for (int mt = 0; mt < 4; mt++)
                af[mt] = *(const short8*)(As + (wm * 64 + mt * 16 + l16) * GSTR + c * 32 + qd * 8);
            #pragma unroll
            for (int nt = 0; nt < 4; nt++)
                bf[nt] = *(const short8*)(Bs + (wn * 64 + nt * 16 + l16) * GSTR + c * 32 + qd * 8);
            #pragma unroll
            for (int mt = 0; mt < 4; mt++)
                #pragma unroll
                for (int nt = 0; nt < 4; nt++)
                    acc[mt][nt] = __builtin_amdgcn_mfma_f32_16x16x32_bf16(
                        af[mt], bf[nt], acc[mt][nt], 0, 0, 0);
        }
        if (!more) break;
        __syncthreads();   // all waves done reading LDS
        #pragma unroll
        for (int i = 0; i < 4; i++) {
            *(ushort8*)(As + rows[i] * GSTR + segs[i]) = ra[i];   // vmcnt wait lands here
            *(ushort8*)(Bs + rows[i] * GSTR + segs[i]) = rb[i];
        }
        __syncthreads();   // staged
    }

    #pragma unroll
    for (int mt = 0; mt < 4; mt++) {
        #pragma unroll
        for (int nt = 0; nt < 4; nt++) {
            int col = bn + wn * 64 + nt * 16 + l16;
            float bv = (kz == 0) ? bias[col] : 0.f;
            #pragma unroll
            for (int r = 0; r < 4; r++) {
                int row = bm + wm * 64 + mt * 16 + qd * 4 + r;
                if (kz != 0) {
                    pacc[(size_t)row * ldo + col] = acc[mt][nt][r];
                    continue;
                }
                float v = acc[mt][nt][r] + bv;
                if (mode == 1) {
                    v += bf2f(resb[(size_t)row * ldr + col]);
                    outf[(size_t)row * ldo + col] = v;
                } else if (mode == 2) {
                    v = 0.5f * v * (1.0f + erff(v * 0.70710678118654752f));
                    outb[(size_t)row * ldo + col] = f2bf(v);
                } else if (mode == 3) {
                    outb[(size_t)row * ldo + col] = f2bf(v);
                } else {
                    outf[(size_t)row * ldo + col] = v;
                }
            }
        }
    }
}

// ---------------- MFMA flash attention, S^T form (P stays in registers) ------------
#define ASTR 72

__global__ __launch_bounds__(256) void attn_mfma(
    const unsigned short* __restrict__ qkv, const float* __restrict__ mask,
    unsigned short* __restrict__ out)
{
    __shared__ __align__(16) unsigned short Ks[64 * ASTR];
    __shared__ __align__(16) unsigned short Vt[64 * ASTR];
    __shared__ float Ms[64];

    const int t    = threadIdx.x;
    const int lane = t & 63;
    const int wv   = t >> 6;
    const int l16  = lane & 15;
    const int quad = lane >> 4;
    const int q0   = blockIdx.x * 64;
    const int bh   = blockIdx.y;
    const int h    = bh % N_HEAD;
    const int b    = bh / N_HEAD;

    const unsigned short* qb = qkv + (size_t)b * SEQ * QKV_LD + h * HEAD_D;
    const unsigned short* kb = qb + 768;
    const unsigned short* vb = qb + 1536;

    const int srow = t >> 2;
    const int sc0  = (t & 3) * 16;
    const int sigrow = (srow & 0x23) | ((srow & 0x04) << 2) | ((srow & 0x18) >> 1);
    const int vslot  = srow ^ ((t & 3) << 3);

    {
        const ushort8* src = (const ushort8*)(qb + (size_t)(q0 + srow) * QKV_LD + sc0);
        *(ushort8*)&Ks[srow * ASTR + sc0]     = src[0];
        *(ushort8*)&Ks[srow * ASTR + sc0 + 8] = src[1];
    }
    __syncthreads();
    short8 bq0 = *(const short8*)&Ks[(wv * 16 + l16) * ASTR + quad * 8];
    short8 bq1 = *(const short8*)&Ks[(wv * 16 + l16) * ASTR + 32 + quad * 8];
    __syncthreads();

    f32x4 o[4];
    #pragma unroll
    for (int i = 0; i < 4; i++) o[i] = (f32x4){0.f, 0.f, 0.f, 0.f};
    float m_st = -INFINITY, l_st = 0.f;

    for (int kt = 0; kt < SEQ / 64; kt++) {
        const int key0 = kt * 64;
        {
            const ushort8* ksrc = (const ushort8*)(kb + (size_t)(key0 + srow) * QKV_LD + sc0);
            *(ushort8*)&Ks[sigrow * ASTR + sc0]     = ksrc[0];
            *(ushort8*)&Ks[sigrow * ASTR + sc0 + 8] = ksrc[1];
            const ushort8* vsrc = (const ushort8*)(vb + (size_t)(key0 + srow) * QKV_LD + sc0);
            ushort8 v0 = vsrc[0], v1 = vsrc[1];
            #pragma unroll
            for (int j = 0; j < 8; j++) Vt[(sc0 + j) * ASTR + vslot] = v0[j];
            #pragma unroll
            for (int j = 0; j < 8; j++) Vt[(sc0 + 8 + j) * ASTR + vslot] = v1[j];
            if (t < 64) Ms[t] = -10000.0f * (1.0f - mask[b * SEQ + key0 + t]);
        }
        __syncthreads();

        f32x4 st[4];
        #pragma unroll
        for (int bi = 0; bi < 4; bi++) {
            const int krow = (bi * 16 + l16) * ASTR;
            short8 k0 = *(const short8*)&Ks[krow + quad * 8];
            short8 k1 = *(const short8*)&Ks[krow + 32 + quad * 8];
            f32x4 z = (f32x4){0.f, 0.f, 0.f, 0.f};
            z = __builtin_amdgcn_mfma_f32_16x16x32_bf16(k0, bq0, z, 0, 0, 0);
            st[bi] = __builtin_amdgcn_mfma_f32_16x16x32_bf16(k1, bq1, z, 0, 0, 0);
        }

        float p[4][4];
        float mx = -3.0e38f;
        #pragma unroll
        for (int bi = 0; bi < 4; bi++) {
            #pragma unroll
            for (int r = 0; r < 4; r++) {
                float s = fmaf(st[bi][r], 0.125f,
                               Ms[((bi >> 1) << 5) + (quad << 3) + ((bi & 1) << 2) + r]);
                p[bi][r] = s;
                mx = fmaxf(mx, s);
            }
        }
        mx = fmaxf(mx, __shfl_xor(mx, 16, 64));
        mx = fmaxf(mx, __shfl_xor(mx, 32, 64));
        float m_new = fmaxf(m_st, mx);
        float alpha = __expf(m_st - m_new);
        m_st = m_new;
        float ls = 0.f;
        #pragma unroll
        for (int bi = 0; bi < 4; bi++) {
            #pragma unroll
            for (int r = 0; r < 4; r++) {
                p[bi][r] = __expf(p[bi][r] - m_new);
                ls += p[bi][r];
            }
        }
        ls += __shfl_xor(ls, 16, 64);
        ls += __shfl_xor(ls, 32, 64);
        l_st = l_st * alpha + ls;

        float ar[4];
        #pragma unroll
        for (int r = 0; r < 4; r++) ar[r] = __shfl(alpha, quad * 4 + r, 64);
        #pragma unroll
        for (int nt = 0; nt < 4; nt++)
            #pragma unroll
            for (int r = 0; r < 4; r++)
                o[nt][r] *= ar[r];

        short8 pf0, pf1;
        #pragma unroll
        for (int bsel = 0; bsel < 2; bsel++) {
            #pragma unroll
            for (int r = 0; r < 4; r++) {
                pf0[bsel * 4 + r] = (short)f2bf(p[bsel][r]);
                pf1[bsel * 4 + r] = (short)f2bf(p[2 + bsel][r]);
            }
        }

        #pragma unroll
        for (int nt = 0; nt < 4; nt++) {
            const int vrow = (nt * 16 + l16) * ASTR;
            short8 v0 = *(const short8*)&Vt[vrow + ((quad * 8) ^ (nt << 3))];
            short8 v1 = *(const short8*)&Vt[vrow + ((32 + quad * 8) ^ (nt << 3))];
            o[nt] = __builtin_amdgcn_mfma_f32_16x16x32_bf16(pf0, v0, o[nt], 0, 0, 0);
            o[nt] = __builtin_amdgcn_mfma_f32_16x16x32_bf16(pf1, v1, o[nt], 0, 0, 0);
        }
        __syncthreads();
    }

    float inv = 1.0f / l_st;
    float ir[4];
    #pragma unroll
    for (int r = 0; r < 4; r++) ir[r] = __shfl(inv, quad * 4 + r, 64);
    #pragma unroll
    for (int nt = 0; nt < 4; nt++) {
        #pragma unroll
        for (int r = 0; r < 4; r++) {
            int qi = q0 + wv * 16 + quad * 4 + r;
            out[(size_t)(b * SEQ + qi) * D_MODEL + h * HEAD_D + nt * 16 + l16] =
                f2bf(o[nt][r] * ir[r]);
        }
    }
}

// ---------------- LayerNorm over 768; optional second f32 input (split-K partial) --
__global__ __launch_bounds__(256) void ln_kernel(
    const float* __restrict__ in, const float* __restrict__ in2,
    const float* __restrict__ g, const float* __restrict__ be,
    float* __restrict__ outf, unsigned short* __restrict__ outb)
{
    const int row = blockIdx.x;
    const int t   = threadIdx.x;
    const float* rp  = in  + (size_t)row * D_MODEL;
    const float* rp2 = in2 ? in2 + (size_t)row * D_MODEL : nullptr;

    float vals[3];
    float s = 0.f, s2 = 0.f;
    #pragma unroll
    for (int i = 0; i < 3; i++) {
        float x = rp[t + i * 256];
        if (rp2) x += rp2[t + i * 256];
        vals[i] = x;
        s += x; s2 += x * x;
    }
    #pragma unroll
    for (int off = 32; off >= 1; off >>= 1) {
        s  += __shfl_xor(s,  off, 64);
        s2 += __shfl_xor(s2, off, 64);
    }
    __shared__ float rs[4], rs2[4];
    __shared__ float mu_s, rstd_s;
    const int wave = t >> 6, lane = t & 63;
    if (lane == 0) { rs[wave] = s; rs2[wave] = s2; }
    __syncthreads();
    if (t == 0) {
        float S1 = rs[0] + rs[1] + rs[2] + rs[3];
        float S2 = rs2[0] + rs2[1] + rs2[2] + rs2[3];
        float mu  = S1 * (1.0f / D_MODEL);
        float var = S2 * (1.0f / D_MODEL) - mu * mu;
        mu_s = mu;
        rstd_s = rsqrtf(var + 1e-12f);
    }
    __syncthreads();
    const float mu = mu_s, rstd = rstd_s;
    #pragma unroll
    for (int i = 0; i < 3; i++) {
        int c = t + i * 256;
        float o = g[c] * (vals[i] - mu) * rstd + be[c];
        if (outf) outf[(size_t)row * D_MODEL + c] = o;
        if (outb) outb[(size_t)row * D_MODEL + c] = f2bf(o);
    }
}

extern "C" void kernel_launch(void* const* d_in, const int* in_sizes, int n_in,
                              void* d_out, int out_size, void* d_ws, size_t ws_size,
                              hipStream_t stream)
{
    const float* x    = (const float*)d_in[0];
    const float* mask = (const float*)d_in[1];
    const float* Wq   = (const float*)d_in[2];
    const float* bq   = (const float*)d_in[3];
    const float* Wk   = (const float*)d_in[4];
    const float* bk   = (const float*)d_in[5];
    const float* Wv   = (const float*)d_in[6];
    const float* bv   = (const float*)d_in[7];
    const float* Wp   = (const float*)d_in[8];
    const float* bp   = (const float*)d_in[9];
    const float* g1   = (const float*)d_in[10];
    const float* be1  = (const float*)d_in[11];
    const float* W1   = (const float*)d_in[12];
    const float* bf1  = (const float*)d_in[13];
    const float* W2   = (const float*)d_in[14];
    const float* bf2  = (const float*)d_in[15];
    const float* g2   = (const float*)d_in[16];
    const float* be2  = (const float*)d_in[17];

    const int M = BATCH * SEQ;   // 4096

    // ---- workspace layout (bytes), ~77.1 MB total ----
    char* ws = (char*)d_ws;
    unsigned short* qkvb  = (unsigned short*)(ws + 0);         // [4096,2304] bf16
    unsigned short* ff1b  = (unsigned short*)(ws + 0);         // [4096,3072] bf16 (qkvb dead)
    unsigned short* xb    = (unsigned short*)(ws + 25165824);  // [4096,768] bf16 (live thru proj)
    unsigned short* hb    = (unsigned short*)(ws + 31457280);  // [4096,768] bf16
    unsigned short* x1b   = (unsigned short*)(ws + 31457280);  // alias (hb dead after proj)
    float*          y0    = (float*)(ws + 37748736);           // [4096,768] f32
    unsigned short* wqkvb = (unsigned short*)(ws + 50331648);  // [2304,768]
    unsigned short* wpb   = (unsigned short*)(ws + 53870592);  // [768,768]
    unsigned short* w1b   = (unsigned short*)(ws + 55050240);  // [3072,768]
    unsigned short* w2b   = (unsigned short*)(ws + 59768832);  // [768,3072]
    float*          bqkv  = (float*)(ws + 64487424);           // [2304]
    float*          p1    = (float*)(ws + 64496640);           // [4096,768] f32 split-K partial

    dim3 blk(256);

    conv_fused<<<dim3(9985), blk, 0, stream>>>(
        x, Wq, Wk, Wv, Wp, W1, W2, bq, bk, bv,
        xb, wqkvb, wpb, w1b, w2b, bqkv);

    // fused QKV GEMM -> bf16
    gemm_bf16<<<dim3(QKV_LD / 128, M / 128, 1), blk, 0, stream>>>(
        xb, D_MODEL, wqkvb, D_MODEL, bqkv, nullptr, 0,
        nullptr, qkvb, nullptr, QKV_LD, M, QKV_LD, D_MODEL, 3);

    // flash attention -> hb (bf16)
    attn_mfma<<<dim3(SEQ / 64, BATCH * N_HEAD), blk, 0, stream>>>(qkvb, mask, hb);

    // proj + residual, split-K x2: y0 (z=0: bias + xb) + p1 (z=1 raw)
    gemm_bf16<<<dim3(D_MODEL / 128, M / 128, 2), blk, 0, stream>>>(
        hb, D_MODEL, wpb, D_MODEL, bp, xb, D_MODEL,
        y0, nullptr, p1, D_MODEL, M, D_MODEL, D_MODEL, 1);

    // LN1 over (y0 + p1) -> x1b (bf16)
    ln_kernel<<<dim3(M), blk, 0, stream>>>(y0, p1, g1, be1, nullptr, x1b);

    // FFN1 + gelu -> ff1b (unsplit; gelu is nonlinear)
    gemm_bf16<<<dim3(D_FF / 128, M / 128, 1), blk, 0, stream>>>(
        x1b, D_MODEL, w1b, D_MODEL, bf1, nullptr, 0,
        nullptr, ff1b, nullptr, D_FF, M, D_FF, D_MODEL, 2);

    // FFN2 + residual, split-K x2: y0 (z=0: bias + x1b) + p1 (z=1 raw)
    gemm_bf16<<<dim3(D_MODEL / 128, M / 128, 2), blk, 0, stream>>>(
        ff1b, D_FF, w2b, D_FF, bf2, x1b, D_MODEL,
        y0, nullptr, p1, D_MODEL, M, D_MODEL, D_FF, 1);

    // LN2 over (y0 + p1) -> out (f32)
    ln_kernel<<<dim3(M), blk, 0, stream>>>(y0, p1, g2, be2, (float*)d_out, nullptr);
}

// Round 8
// 371.014 us; speedup vs baseline: 1.2820x; 1.2820x over previous
//
#include <hip/hip_runtime.h>
#include <hip/hip_bf16.h>
#include <math.h>

// Problem constants
#define D_MODEL 768
#define D_FF    3072
#define N_HEAD  12
#define HEAD_D  64
#define BATCH   2
#define SEQ     2048
#define QKV_LD  2304

typedef __attribute__((ext_vector_type(8))) short short8;            // 8 bf16 (4 VGPRs)
typedef __attribute__((ext_vector_type(8))) unsigned short ushort8;  // 16B staging
typedef __attribute__((ext_vector_type(4))) float f32x4;             // MFMA C/D frag

__device__ inline unsigned short f2bf(float f) {
    union { __hip_bfloat16 b; unsigned short u; } cv;
    cv.b = __float2bfloat16(f);
    return cv.u;
}

__device__ inline float bf2f(unsigned short u) {
    union { unsigned int i; float f; } cv;
    cv.i = ((unsigned int)u) << 16;
    return cv.f;
}

__device__ inline void async_load16(const void* g, void* l) {
    __builtin_amdgcn_global_load_lds(
        (const __attribute__((address_space(1))) void*)g,
        (__attribute__((address_space(3))) void*)l, 16, 0, 0);
}

// ---------------- fused fp32->bf16 conversions + bias pack -------------------------
__global__ __launch_bounds__(256) void conv_fused(
    const float* __restrict__ x,
    const float* __restrict__ Wq, const float* __restrict__ Wk,
    const float* __restrict__ Wv, const float* __restrict__ Wp,
    const float* __restrict__ W1, const float* __restrict__ W2,
    const float* __restrict__ bq, const float* __restrict__ bk,
    const float* __restrict__ bv,
    unsigned short* __restrict__ xb, unsigned short* __restrict__ wqkvb,
    unsigned short* __restrict__ wpb, unsigned short* __restrict__ w1b,
    unsigned short* __restrict__ w2b, float* __restrict__ bqkv)
{
    int bid = blockIdx.x;
    const float* src; unsigned short* dst; int base;
    if      (bid < 3072) { src = x;  dst = xb;              base = bid;        }
    else if (bid < 3648) { src = Wq; dst = wqkvb;           base = bid - 3072; }
    else if (bid < 4224) { src = Wk; dst = wqkvb + 589824;  base = bid - 3648; }
    else if (bid < 4800) { src = Wv; dst = wqkvb + 1179648; base = bid - 4224; }
    else if (bid < 5376) { src = Wp; dst = wpb;             base = bid - 4800; }
    else if (bid < 7680) { src = W1; dst = w1b;             base = bid - 5376; }
    else if (bid < 9984) { src = W2; dst = w2b;             base = bid - 7680; }
    else {
        for (int j = threadIdx.x; j < QKV_LD; j += 256)
            bqkv[j] = (j < 768) ? bq[j] : (j < 1536) ? bk[j - 768] : bv[j - 1536];
        return;
    }
    int i = (base * 256 + threadIdx.x) * 4;
    float4 v = *(const float4*)(src + i);
    ushort4 o4;
    o4.x = f2bf(v.x); o4.y = f2bf(v.y); o4.z = f2bf(v.z); o4.w = f2bf(v.w);
    *(ushort4*)(dst + i) = o4;
}

// ---------------- bf16 MFMA GEMM: 3-stage global_load_lds pipeline -----------------
// C[m,n] = sum_k A[m,k]*W[n,k]; A:[M,K] bf16, W:[N,K] bf16 (NT).
// K-loop uses RAW s_barrier + explicit s_waitcnt vmcnt(N) (never draining the
// prefetch queue): stage s holds tile it, while tiles it+1, it+2 stay in flight.
// Each wave issues exactly 4 global_load_lds per tile, so vmcnt(8) == "my 4
// oldest (current stage) landed"; barrier makes that collective.
// gridDim.z = K-splits; z==0 does the epilogue, z>0 writes raw f32 partial to pacc.
// mode 0: outf = acc + bias
// mode 1: outf = acc + bias + bf16(resb)
// mode 2: outb = bf16(gelu_exact(acc + bias))   (do not split-K)
// mode 3: outb = bf16(acc + bias)
#define NSTAGE 3

__global__ __launch_bounds__(256) void gemm_bf16(
    const unsigned short* __restrict__ A, int lda,
    const unsigned short* __restrict__ W, int ldw,
    const float* __restrict__ bias,
    const unsigned short* __restrict__ resb, int ldr,
    float* __restrict__ outf, unsigned short* __restrict__ outb,
    float* __restrict__ pacc, int ldo,
    int M, int N, int K, int mode)
{
    __shared__ unsigned short As[NSTAGE][128 * 32];   // 8 KB per stage
    __shared__ unsigned short Bs[NSTAGE][128 * 32];

    const int t    = threadIdx.x;
    const int lane = t & 63;
    const int wv   = t >> 6;
    const int wm   = wv >> 1;
    const int wn   = wv & 1;
    const int bm   = blockIdx.y * 128;
    const int bn   = blockIdx.x * 128;
    const int kz   = blockIdx.z;
    const int Kc   = K / gridDim.z;

    const int qd   = lane >> 4;
    const int l16  = lane & 15;

    f32x4 acc[4][4];
    #pragma unroll
    for (int i = 0; i < 4; i++)
        #pragma unroll
        for (int j = 0; j < 4; j++)
            acc[i][j] = (f32x4){0.f, 0.f, 0.f, 0.f};

    // staging: chunk c = wv*2+i covers LDS rows c*16..+15; lane l -> +l*16B
    const int srow = lane >> 2;
    const int sseg = (lane & 3) * 8;
    const int r0   = (wv * 2 + 0) * 16 + srow;
    const int r1   = (wv * 2 + 1) * 16 + srow;
    const size_t gA0 = (size_t)(bm + r0) * lda + sseg;
    const size_t gA1 = (size_t)(bm + r1) * lda + sseg;
    const size_t gB0 = (size_t)(bn + r0) * ldw + sseg;
    const size_t gB1 = (size_t)(bn + r1) * ldw + sseg;
    const int c0 = (wv * 2 + 0) * 512;
    const int c1 = (wv * 2 + 1) * 512;

    const int kbeg  = kz * Kc;
    const int niter = Kc / 32;

    // prologue: fill up to 3 stages (4 loads per wave per stage)
    async_load16(A + gA0 + kbeg, &As[0][c0]);
    async_load16(W + gB0 + kbeg, &Bs[0][c0]);
    async_load16(A + gA1 + kbeg, &As[0][c1]);
    async_load16(W + gB1 + kbeg, &Bs[0][c1]);
    if (niter > 1) {
        async_load16(A + gA0 + kbeg + 32, &As[1][c0]);
        async_load16(W + gB0 + kbeg + 32, &Bs[1][c0]);
        async_load16(A + gA1 + kbeg + 32, &As[1][c1]);
        async_load16(W + gB1 + kbeg + 32, &Bs[1][c1]);
    }
    if (niter > 2) {
        async_load16(A + gA0 + kbeg + 64, &As[2][c0]);
        async_load16(W + gB0 + kbeg + 64, &Bs[2][c0]);
        async_load16(A + gA1 + kbeg + 64, &As[2][c1]);
        async_load16(W + gB1 + kbeg + 64, &Bs[2][c1]);
    }

    int stage = 0;
    for (int it = 0; it < niter; it++) {
        // wait for current stage only: keep the 2 newer stages in flight
        const int rem = niter - 1 - it;            // tiles in flight beyond current
        if (rem >= 2)      __builtin_amdgcn_s_waitcnt(0x0F78);  // vmcnt(8)
        else if (rem == 1) __builtin_amdgcn_s_waitcnt(0x0F74);  // vmcnt(4)
        else               __builtin_amdgcn_s_waitcnt(0x0F70);  // vmcnt(0)
        __builtin_amdgcn_s_barrier();              // stage ready on all waves

        short8 af[4], bf[4];
        #pragma unroll
        for (int mt = 0; mt < 4; mt++)
            af[mt] = *(const short8*)(&As[stage][(wm * 64 + mt * 16 + l16) * 32 + qd * 8]);
        #pragma unroll
        for (int nt = 0; nt < 4; nt++)
            bf[nt] = *(const short8*)(&Bs[stage][(wn * 64 + nt * 16 + l16) * 32 + qd * 8]);
        #pragma unroll
        for (int mt = 0; mt < 4; mt++)
            #pragma unroll
            for (int nt = 0; nt < 4; nt++)
                acc[mt][nt] = __builtin_amdgcn_mfma_f32_16x16x32_bf16(
                    af[mt], bf[nt], acc[mt][nt], 0, 0, 0);

        __builtin_amdgcn_s_barrier();              // all waves done reading this stage
        if (it + NSTAGE < niter) {
            const int kn = kbeg + (it + NSTAGE) * 32;
            async_load16(A + gA0 + kn, &As[stage][c0]);
            async_load16(W + gB0 + kn, &Bs[stage][c0]);
            async_load16(A + gA1 + kn, &As[stage][c1]);
            async_load16(W + gB1 + kn, &Bs[stage][c1]);
        }
        stage = (stage == NSTAGE - 1) ? 0 : stage + 1;
    }

    #pragma unroll
    for (int mt = 0; mt < 4; mt++) {
        #pragma unroll
        for (int nt = 0; nt < 4; nt++) {
            int col = bn + wn * 64 + nt * 16 + l16;
            float bv = (kz == 0) ? bias[col] : 0.f;
            #pragma unroll
            for (int r = 0; r < 4; r++) {
                int row = bm + wm * 64 + mt * 16 + qd * 4 + r;
                if (kz != 0) {
                    pacc[(size_t)row * ldo + col] = acc[mt][nt][r];
                    continue;
                }
                float v = acc[mt][nt][r] + bv;
                if (mode == 1) {
                    v += bf2f(resb[(size_t)row * ldr + col]);
                    outf[(size_t)row * ldo + col] = v;
                } else if (mode == 2) {
                    v = 0.5f * v * (1.0f + erff(v * 0.70710678118654752f));
                    outb[(size_t)row * ldo + col] = f2bf(v);
                } else if (mode == 3) {
                    outb[(size_t)row * ldo + col] = f2bf(v);
                } else {
                    outf[(size_t)row * ldo + col] = v;
                }
            }
        }
    }
}

// ---------------- MFMA flash attention, S^T form (P stays in registers) ------------
#define ASTR 72

__global__ __launch_bounds__(256) void attn_mfma(
    const unsigned short* __restrict__ qkv, const float* __restrict__ mask,
    unsigned short* __restrict__ out)
{
    __shared__ __align__(16) unsigned short Ks[64 * ASTR];
    __shared__ __align__(16) unsigned short Vt[64 * ASTR];
    __shared__ float Ms[64];

    const int t    = threadIdx.x;
    const int lane = t & 63;
    const int wv   = t >> 6;
    const int l16  = lane & 15;
    const int quad = lane >> 4;
    const int q0   = blockIdx.x * 64;
    const int bh   = blockIdx.y;
    const int h    = bh % N_HEAD;
    const int b    = bh / N_HEAD;

    const unsigned short* qb = qkv + (size_t)b * SEQ * QKV_LD + h * HEAD_D;
    const unsigned short* kb = qb + 768;
    const unsigned short* vb = qb + 1536;

    const int srow = t >> 2;
    const int sc0  = (t & 3) * 16;
    const int sigrow = (srow & 0x23) | ((srow & 0x04) << 2) | ((srow & 0x18) >> 1);
    const int vslot  = srow ^ ((t & 3) << 3);

    {
        const ushort8* src = (const ushort8*)(qb + (size_t)(q0 + srow) * QKV_LD + sc0);
        *(ushort8*)&Ks[srow * ASTR + sc0]     = src[0];
        *(ushort8*)&Ks[srow * ASTR + sc0 + 8] = src[1];
    }
    __syncthreads();
    short8 bq0 = *(const short8*)&Ks[(wv * 16 + l16) * ASTR + quad * 8];
    short8 bq1 = *(const short8*)&Ks[(wv * 16 + l16) * ASTR + 32 + quad * 8];
    __syncthreads();

    f32x4 o[4];
    #pragma unroll
    for (int i = 0; i < 4; i++) o[i] = (f32x4){0.f, 0.f, 0.f, 0.f};
    float m_st = -INFINITY, l_st = 0.f;

    for (int kt = 0; kt < SEQ / 64; kt++) {
        const int key0 = kt * 64;
        {
            const ushort8* ksrc = (const ushort8*)(kb + (size_t)(key0 + srow) * QKV_LD + sc0);
            *(ushort8*)&Ks[sigrow * ASTR + sc0]     = ksrc[0];
            *(ushort8*)&Ks[sigrow * ASTR + sc0 + 8] = ksrc[1];
            const ushort8* vsrc = (const ushort8*)(vb + (size_t)(key0 + srow) * QKV_LD + sc0);
            ushort8 v0 = vsrc[0], v1 = vsrc[1];
            #pragma unroll
            for (int j = 0; j < 8; j++) Vt[(sc0 + j) * ASTR + vslot] = v0[j];
            #pragma unroll
            for (int j = 0; j < 8; j++) Vt[(sc0 + 8 + j) * ASTR + vslot] = v1[j];
            if (t < 64) Ms[t] = -10000.0f * (1.0f - mask[b * SEQ + key0 + t]);
        }
        __syncthreads();

        f32x4 st[4];
        #pragma unroll
        for (int bi = 0; bi < 4; bi++) {
            const int krow = (bi * 16 + l16) * ASTR;
            short8 k0 = *(const short8*)&Ks[krow + quad * 8];
            short8 k1 = *(const short8*)&Ks[krow + 32 + quad * 8];
            f32x4 z = (f32x4){0.f, 0.f, 0.f, 0.f};
            z = __builtin_amdgcn_mfma_f32_16x16x32_bf16(k0, bq0, z, 0, 0, 0);
            st[bi] = __builtin_amdgcn_mfma_f32_16x16x32_bf16(k1, bq1, z, 0, 0, 0);
        }

        float p[4][4];
        float mx = -3.0e38f;
        #pragma unroll
        for (int bi = 0; bi < 4; bi++) {
            #pragma unroll
            for (int r = 0; r < 4; r++) {
                float s = fmaf(st[bi][r], 0.125f,
                               Ms[((bi >> 1) << 5) + (quad << 3) + ((bi & 1) << 2) + r]);
                p[bi][r] = s;
                mx = fmaxf(mx, s);
            }
        }
        mx = fmaxf(mx, __shfl_xor(mx, 16, 64));
        mx = fmaxf(mx, __shfl_xor(mx, 32, 64));
        float m_new = fmaxf(m_st, mx);
        float alpha = __expf(m_st - m_new);
        m_st = m_new;
        float ls = 0.f;
        #pragma unroll
        for (int bi = 0; bi < 4; bi++) {
            #pragma unroll
            for (int r = 0; r < 4; r++) {
                p[bi][r] = __expf(p[bi][r] - m_new);
                ls += p[bi][r];
            }
        }
        ls += __shfl_xor(ls, 16, 64);
        ls += __shfl_xor(ls, 32, 64);
        l_st = l_st * alpha + ls;

        float ar[4];
        #pragma unroll
        for (int r = 0; r < 4; r++) ar[r] = __shfl(alpha, quad * 4 + r, 64);
        #pragma unroll
        for (int nt = 0; nt < 4; nt++)
            #pragma unroll
            for (int r = 0; r < 4; r++)
                o[nt][r] *= ar[r];

        short8 pf0, pf1;
        #pragma unroll
        for (int bsel = 0; bsel < 2; bsel++) {
            #pragma unroll
            for (int r = 0; r < 4; r++) {
                pf0[bsel * 4 + r] = (short)f2bf(p[bsel][r]);
                pf1[bsel * 4 + r] = (short)f2bf(p[2 + bsel][r]);
            }
        }

        #pragma unroll
        for (int nt = 0; nt < 4; nt++) {
            const int vrow = (nt * 16 + l16) * ASTR;
            short8 v0 = *(const short8*)&Vt[vrow + ((quad * 8) ^ (nt << 3))];
            short8 v1 = *(const short8*)&Vt[vrow + ((32 + quad * 8) ^ (nt << 3))];
            o[nt] = __builtin_amdgcn_mfma_f32_16x16x32_bf16(pf0, v0, o[nt], 0, 0, 0);
            o[nt] = __builtin_amdgcn_mfma_f32_16x16x32_bf16(pf1, v1, o[nt], 0, 0, 0);
        }
        __syncthreads();
    }

    float inv = 1.0f / l_st;
    float ir[4];
    #pragma unroll
    for (int r = 0; r < 4; r++) ir[r] = __shfl(inv, quad * 4 + r, 64);
    #pragma unroll
    for (int nt = 0; nt < 4; nt++) {
        #pragma unroll
        for (int r = 0; r < 4; r++) {
            int qi = q0 + wv * 16 + quad * 4 + r;
            out[(size_t)(b * SEQ + qi) * D_MODEL + h * HEAD_D + nt * 16 + l16] =
                f2bf(o[nt][r] * ir[r]);
        }
    }
}

// ---------------- LayerNorm over 768; optional second f32 input (split-K partial) --
__global__ __launch_bounds__(256) void ln_kernel(
    const float* __restrict__ in, const float* __restrict__ in2,
    const float* __restrict__ g, const float* __restrict__ be,
    float* __restrict__ outf, unsigned short* __restrict__ outb)
{
    const int row = blockIdx.x;
    const int t   = threadIdx.x;
    const float* rp  = in  + (size_t)row * D_MODEL;
    const float* rp2 = in2 ? in2 + (size_t)row * D_MODEL : nullptr;

    float vals[3];
    float s = 0.f, s2 = 0.f;
    #pragma unroll
    for (int i = 0; i < 3; i++) {
        float x = rp[t + i * 256];
        if (rp2) x += rp2[t + i * 256];
        vals[i] = x;
        s += x; s2 += x * x;
    }
    #pragma unroll
    for (int off = 32; off >= 1; off >>= 1) {
        s  += __shfl_xor(s,  off, 64);
        s2 += __shfl_xor(s2, off, 64);
    }
    __shared__ float rs[4], rs2[4];
    __shared__ float mu_s, rstd_s;
    const int wave = t >> 6, lane = t & 63;
    if (lane == 0) { rs[wave] = s; rs2[wave] = s2; }
    __syncthreads();
    if (t == 0) {
        float S1 = rs[0] + rs[1] + rs[2] + rs[3];
        float S2 = rs2[0] + rs2[1] + rs2[2] + rs2[3];
        float mu  = S1 * (1.0f / D_MODEL);
        float var = S2 * (1.0f / D_MODEL) - mu * mu;
        mu_s = mu;
        rstd_s = rsqrtf(var + 1e-12f);
    }
    __syncthreads();
    const float mu = mu_s, rstd = rstd_s;
    #pragma unroll
    for (int i = 0; i < 3; i++) {
        int c = t + i * 256;
        float o = g[c] * (vals[i] - mu) * rstd + be[c];
        if (outf) outf[(size_t)row * D_MODEL + c] = o;
        if (outb) outb[(size_t)row * D_MODEL + c] = f2bf(o);
    }
}

extern "C" void kernel_launch(void* const* d_in, const int* in_sizes, int n_in,
                              void* d_out, int out_size, void* d_ws, size_t ws_size,
                              hipStream_t stream)
{
    const float* x    = (const float*)d_in[0];
    const float* mask = (const float*)d_in[1];
    const float* Wq   = (const float*)d_in[2];
    const float* bq   = (const float*)d_in[3];
    const float* Wk   = (const float*)d_in[4];
    const float* bk   = (const float*)d_in[5];
    const float* Wv   = (const float*)d_in[6];
    const float* bv   = (const float*)d_in[7];
    const float* Wp   = (const float*)d_in[8];
    const float* bp   = (const float*)d_in[9];
    const float* g1   = (const float*)d_in[10];
    const float* be1  = (const float*)d_in[11];
    const float* W1   = (const float*)d_in[12];
    const float* bf1  = (const float*)d_in[13];
    const float* W2   = (const float*)d_in[14];
    const float* bf2  = (const float*)d_in[15];
    const float* g2   = (const float*)d_in[16];
    const float* be2  = (const float*)d_in[17];

    const int M = BATCH * SEQ;   // 4096

    // ---- workspace layout (bytes), ~77.1 MB total ----
    char* ws = (char*)d_ws;
    unsigned short* qkvb  = (unsigned short*)(ws + 0);         // [4096,2304] bf16
    unsigned short* ff1b  = (unsigned short*)(ws + 0);         // [4096,3072] bf16 (qkvb dead)
    unsigned short* xb    = (unsigned short*)(ws + 25165824);  // [4096,768] bf16 (live thru proj)
    unsigned short* hb    = (unsigned short*)(ws + 31457280);  // [4096,768] bf16
    unsigned short* x1b   = (unsigned short*)(ws + 31457280);  // alias (hb dead after proj)
    float*          y0    = (float*)(ws + 37748736);           // [4096,768] f32
    unsigned short* wqkvb = (unsigned short*)(ws + 50331648);  // [2304,768]
    unsigned short* wpb   = (unsigned short*)(ws + 53870592);  // [768,768]
    unsigned short* w1b   = (unsigned short*)(ws + 55050240);  // [3072,768]
    unsigned short* w2b   = (unsigned short*)(ws + 59768832);  // [768,3072]
    float*          bqkv  = (float*)(ws + 64487424);           // [2304]
    float*          p1    = (float*)(ws + 64496640);           // [4096,768] f32 split-K partial

    dim3 blk(256);

    conv_fused<<<dim3(9985), blk, 0, stream>>>(
        x, Wq, Wk, Wv, Wp, W1, W2, bq, bk, bv,
        xb, wqkvb, wpb, w1b, w2b, bqkv);

    // fused QKV GEMM -> bf16
    gemm_bf16<<<dim3(QKV_LD / 128, M / 128, 1), blk, 0, stream>>>(
        xb, D_MODEL, wqkvb, D_MODEL, bqkv, nullptr, 0,
        nullptr, qkvb, nullptr, QKV_LD, M, QKV_LD, D_MODEL, 3);

    // flash attention -> hb (bf16)
    attn_mfma<<<dim3(SEQ / 64, BATCH * N_HEAD), blk, 0, stream>>>(qkvb, mask, hb);

    // proj + residual, split-K x2: y0 (z=0: bias + xb) + p1 (z=1 raw)
    gemm_bf16<<<dim3(D_MODEL / 128, M / 128, 2), blk, 0, stream>>>(
        hb, D_MODEL, wpb, D_MODEL, bp, xb, D_MODEL,
        y0, nullptr, p1, D_MODEL, M, D_MODEL, D_MODEL, 1);

    // LN1 over (y0 + p1) -> x1b (bf16)
    ln_kernel<<<dim3(M), blk, 0, stream>>>(y0, p1, g1, be1, nullptr, x1b);

    // FFN1 + gelu -> ff1b (unsplit; gelu is nonlinear)
    gemm_bf16<<<dim3(D_FF / 128, M / 128, 1), blk, 0, stream>>>(
        x1b, D_MODEL, w1b, D_MODEL, bf1, nullptr, 0,
        nullptr, ff1b, nullptr, D_FF, M, D_FF, D_MODEL, 2);

    // FFN2 + residual, split-K x2: y0 (z=0: bias + x1b) + p1 (z=1 raw)
    gemm_bf16<<<dim3(D_MODEL / 128, M / 128, 2), blk, 0, stream>>>(
        ff1b, D_FF, w2b, D_FF, bf2, x1b, D_MODEL,
        y0, nullptr, p1, D_MODEL, M, D_MODEL, D_FF, 1);

    // LN2 over (y0 + p1) -> out (f32)
    ln_kernel<<<dim3(M), blk, 0, stream>>>(y0, p1, g2, be2, (float*)d_out, nullptr);
}

// Round 9
// 367.297 us; speedup vs baseline: 1.2950x; 1.0101x over previous
//
#include <hip/hip_runtime.h>
#include <hip/hip_bf16.h>
#include <math.h>

// Problem constants
#define D_MODEL 768
#define D_FF    3072
#define N_HEAD  12
#define HEAD_D  64
#define BATCH   2
#define SEQ     2048
#define QKV_LD  2304

typedef __attribute__((ext_vector_type(8))) short short8;            // 8 bf16 (4 VGPRs)
typedef __attribute__((ext_vector_type(8))) unsigned short ushort8;  // 16B staging
typedef __attribute__((ext_vector_type(4))) float f32x4;             // MFMA C/D frag

__device__ inline unsigned short f2bf(float f) {
    union { __hip_bfloat16 b; unsigned short u; } cv;
    cv.b = __float2bfloat16(f);
    return cv.u;
}

__device__ inline float bf2f(unsigned short u) {
    union { unsigned int i; float f; } cv;
    cv.i = ((unsigned int)u) << 16;
    return cv.f;
}

__device__ inline void async_load16(const void* g, void* l) {
    __builtin_amdgcn_global_load_lds(
        (const __attribute__((address_space(1))) void*)g,
        (__attribute__((address_space(3))) void*)l, 16, 0, 0);
}

// ---------------- fused fp32->bf16 conversions + bias pack -------------------------
__global__ __launch_bounds__(256) void conv_fused(
    const float* __restrict__ x,
    const float* __restrict__ Wq, const float* __restrict__ Wk,
    const float* __restrict__ Wv, const float* __restrict__ Wp,
    const float* __restrict__ W1, const float* __restrict__ W2,
    const float* __restrict__ bq, const float* __restrict__ bk,
    const float* __restrict__ bv,
    unsigned short* __restrict__ xb, unsigned short* __restrict__ wqkvb,
    unsigned short* __restrict__ wpb, unsigned short* __restrict__ w1b,
    unsigned short* __restrict__ w2b, float* __restrict__ bqkv)
{
    int bid = blockIdx.x;
    const float* src; unsigned short* dst; int base;
    if      (bid < 3072) { src = x;  dst = xb;              base = bid;        }
    else if (bid < 3648) { src = Wq; dst = wqkvb;           base = bid - 3072; }
    else if (bid < 4224) { src = Wk; dst = wqkvb + 589824;  base = bid - 3648; }
    else if (bid < 4800) { src = Wv; dst = wqkvb + 1179648; base = bid - 4224; }
    else if (bid < 5376) { src = Wp; dst = wpb;             base = bid - 4800; }
    else if (bid < 7680) { src = W1; dst = w1b;             base = bid - 5376; }
    else if (bid < 9984) { src = W2; dst = w2b;             base = bid - 7680; }
    else {
        for (int j = threadIdx.x; j < QKV_LD; j += 256)
            bqkv[j] = (j < 768) ? bq[j] : (j < 1536) ? bk[j - 768] : bv[j - 1536];
        return;
    }
    int i = (base * 256 + threadIdx.x) * 4;
    float4 v = *(const float4*)(src + i);
    ushort4 o4;
    o4.x = f2bf(v.x); o4.y = f2bf(v.y); o4.z = f2bf(v.z); o4.w = f2bf(v.w);
    *(ushort4*)(dst + i) = o4;
}

// ---------------- bf16 MFMA GEMM: 3-stage pipeline, ONE barrier per iter -----------
// C[m,n] = sum_k A[m,k]*W[n,k]; A:[M,K] bf16, W:[N,K] bf16 (NT).
// Loop invariant: stages hold tiles {it, it+1, it+2-in-flight}. Per iter:
// vmcnt(4) (tile it landed; it+1 stays in flight) -> s_barrier -> issue tile it+2
// into the stage freed at it-1 -> MFMA on tile it. One barrier per iter.
// gridDim.z = K-splits; z==0 does the epilogue, z>0 writes raw f32 partial to pacc.
// mode 0: outf=acc+bias   1: +bf16 res   2: bf16(gelu(acc+bias))   3: bf16(acc+bias)
#define NSTAGE 3

__global__ __launch_bounds__(256) void gemm_bf16(
    const unsigned short* __restrict__ A, int lda,
    const unsigned short* __restrict__ W, int ldw,
    const float* __restrict__ bias,
    const unsigned short* __restrict__ resb, int ldr,
    float* __restrict__ outf, unsigned short* __restrict__ outb,
    float* __restrict__ pacc, int ldo,
    int M, int N, int K, int mode)
{
    __shared__ unsigned short As[NSTAGE][128 * 32];   // 8 KB per stage
    __shared__ unsigned short Bs[NSTAGE][128 * 32];

    const int t    = threadIdx.x;
    const int lane = t & 63;
    const int wv   = t >> 6;
    const int wm   = wv >> 1;
    const int wn   = wv & 1;
    const int bm   = blockIdx.y * 128;
    const int bn   = blockIdx.x * 128;
    const int kz   = blockIdx.z;
    const int Kc   = K / gridDim.z;

    const int qd   = lane >> 4;
    const int l16  = lane & 15;

    f32x4 acc[4][4];
    #pragma unroll
    for (int i = 0; i < 4; i++)
        #pragma unroll
        for (int j = 0; j < 4; j++)
            acc[i][j] = (f32x4){0.f, 0.f, 0.f, 0.f};

    // staging: chunk c = wv*2+i covers LDS rows c*16..+15; lane l -> +l*16B
    const int srow = lane >> 2;
    const int sseg = (lane & 3) * 8;
    const int r0   = (wv * 2 + 0) * 16 + srow;
    const int r1   = (wv * 2 + 1) * 16 + srow;
    const size_t gA0 = (size_t)(bm + r0) * lda + sseg;
    const size_t gA1 = (size_t)(bm + r1) * lda + sseg;
    const size_t gB0 = (size_t)(bn + r0) * ldw + sseg;
    const size_t gB1 = (size_t)(bn + r1) * ldw + sseg;
    const int c0 = (wv * 2 + 0) * 512;
    const int c1 = (wv * 2 + 1) * 512;

    const int kbeg  = kz * Kc;
    const int niter = Kc / 32;

    // prologue: tiles 0,1
    async_load16(A + gA0 + kbeg, &As[0][c0]);
    async_load16(W + gB0 + kbeg, &Bs[0][c0]);
    async_load16(A + gA1 + kbeg, &As[0][c1]);
    async_load16(W + gB1 + kbeg, &Bs[0][c1]);
    if (niter > 1) {
        async_load16(A + gA0 + kbeg + 32, &As[1][c0]);
        async_load16(W + gB0 + kbeg + 32, &Bs[1][c0]);
        async_load16(A + gA1 + kbeg + 32, &As[1][c1]);
        async_load16(W + gB1 + kbeg + 32, &Bs[1][c1]);
    }

    int stage = 0;
    for (int it = 0; it < niter; it++) {
        if (it + 1 < niter) __builtin_amdgcn_s_waitcnt(0x0F74);  // vmcnt(4)
        else                __builtin_amdgcn_s_waitcnt(0x0F70);  // vmcnt(0)
        __builtin_amdgcn_s_barrier();   // tile it ready everywhere; stage (it-1)%3 free

        if (it + 2 < niter) {
            const int sn = (stage + 2 >= NSTAGE) ? stage + 2 - NSTAGE : stage + 2;
            const int kn = kbeg + (it + 2) * 32;
            async_load16(A + gA0 + kn, &As[sn][c0]);
            async_load16(W + gB0 + kn, &Bs[sn][c0]);
            async_load16(A + gA1 + kn, &As[sn][c1]);
            async_load16(W + gB1 + kn, &Bs[sn][c1]);
        }

        short8 af[4], bf[4];
        #pragma unroll
        for (int mt = 0; mt < 4; mt++)
            af[mt] = *(const short8*)(&As[stage][(wm * 64 + mt * 16 + l16) * 32 + qd * 8]);
        #pragma unroll
        for (int nt = 0; nt < 4; nt++)
            bf[nt] = *(const short8*)(&Bs[stage][(wn * 64 + nt * 16 + l16) * 32 + qd * 8]);
        #pragma unroll
        for (int mt = 0; mt < 4; mt++)
            #pragma unroll
            for (int nt = 0; nt < 4; nt++)
                acc[mt][nt] = __builtin_amdgcn_mfma_f32_16x16x32_bf16(
                    af[mt], bf[nt], acc[mt][nt], 0, 0, 0);

        stage = (stage == NSTAGE - 1) ? 0 : stage + 1;
    }

    #pragma unroll
    for (int mt = 0; mt < 4; mt++) {
        #pragma unroll
        for (int nt = 0; nt < 4; nt++) {
            int col = bn + wn * 64 + nt * 16 + l16;
            float bv = (kz == 0) ? bias[col] : 0.f;
            #pragma unroll
            for (int r = 0; r < 4; r++) {
                int row = bm + wm * 64 + mt * 16 + qd * 4 + r;
                if (kz != 0) {
                    pacc[(size_t)row * ldo + col] = acc[mt][nt][r];
                    continue;
                }
                float v = acc[mt][nt][r] + bv;
                if (mode == 1) {
                    v += bf2f(resb[(size_t)row * ldr + col]);
                    outf[(size_t)row * ldo + col] = v;
                } else if (mode == 2) {
                    v = 0.5f * v * (1.0f + erff(v * 0.70710678118654752f));
                    outb[(size_t)row * ldo + col] = f2bf(v);
                } else if (mode == 3) {
                    outb[(size_t)row * ldo + col] = f2bf(v);
                } else {
                    outf[(size_t)row * ldo + col] = v;
                }
            }
        }
    }
}

// ---------------- one-shot V transpose: qkv V-part -> vT[b,h,d,s] ------------------
__global__ __launch_bounds__(256) void vtrans(
    const unsigned short* __restrict__ qkv, unsigned short* __restrict__ vT)
{
    __shared__ unsigned short T[64 * 72];
    const int t   = threadIdx.x;
    const int kt  = blockIdx.x;          // key tile
    const int bh  = blockIdx.y;
    const int h   = bh % N_HEAD;
    const int b   = bh / N_HEAD;
    const int row = t >> 2;              // token within tile
    const int c0  = (t & 3) * 16;        // dim start

    const unsigned short* src =
        qkv + (size_t)(b * SEQ + kt * 64 + row) * QKV_LD + 1536 + h * HEAD_D + c0;
    *(ushort8*)&T[row * 72 + c0]     = *(const ushort8*)src;
    *(ushort8*)&T[row * 72 + c0 + 8] = *(const ushort8*)(src + 8);
    __syncthreads();

    const int d = t >> 2;                // dim row to write
    ushort8 o0, o1;
    #pragma unroll
    for (int j = 0; j < 8; j++) o0[j] = T[(c0 + j) * 72 + d];
    #pragma unroll
    for (int j = 0; j < 8; j++) o1[j] = T[(c0 + 8 + j) * 72 + d];
    unsigned short* dst = vT + ((size_t)bh * HEAD_D + d) * SEQ + kt * 64 + c0;
    *(ushort8*)dst       = o0;
    *(ushort8*)(dst + 8) = o1;
}

// ---------------- MFMA flash attention, S^T form + reg-prefetch --------------------
// K from qkv (sigma-permuted rows); V from pre-transposed vT (natural dim rows).
#define ASTR 72

__global__ __launch_bounds__(256) void attn_mfma(
    const unsigned short* __restrict__ qkv, const unsigned short* __restrict__ vT,
    const float* __restrict__ mask, unsigned short* __restrict__ out)
{
    __shared__ __align__(16) unsigned short Ks[64 * ASTR];
    __shared__ __align__(16) unsigned short Vt[64 * ASTR];
    __shared__ float Ms[64];

    const int t    = threadIdx.x;
    const int lane = t & 63;
    const int wv   = t >> 6;
    const int l16  = lane & 15;
    const int quad = lane >> 4;
    const int q0   = blockIdx.x * 64;
    const int bh   = blockIdx.y;
    const int h    = bh % N_HEAD;
    const int b    = bh / N_HEAD;

    const unsigned short* qb  = qkv + (size_t)b * SEQ * QKV_LD + h * HEAD_D;
    const unsigned short* kb  = qb + 768;
    const unsigned short* vtb = vT + (size_t)bh * HEAD_D * SEQ;

    const int srow = t >> 2;          // staged key row / dim row (0..63)
    const int sc0  = (t & 3) * 16;
    const int sigrow = (srow & 0x23) | ((srow & 0x04) << 2) | ((srow & 0x18) >> 1);

    // ---- stage Q tile (natural rows), pull Q B-frags ----
    {
        const ushort8* src = (const ushort8*)(qb + (size_t)(q0 + srow) * QKV_LD + sc0);
        *(ushort8*)&Ks[srow * ASTR + sc0]     = src[0];
        *(ushort8*)&Ks[srow * ASTR + sc0 + 8] = src[1];
    }
    __syncthreads();
    short8 bq0 = *(const short8*)&Ks[(wv * 16 + l16) * ASTR + quad * 8];
    short8 bq1 = *(const short8*)&Ks[(wv * 16 + l16) * ASTR + 32 + quad * 8];
    __syncthreads();

    f32x4 o[4];
    #pragma unroll
    for (int i = 0; i < 4; i++) o[i] = (f32x4){0.f, 0.f, 0.f, 0.f};
    float m_st = -INFINITY, l_st = 0.f;

    // prefetch tile 0 into registers
    ushort8 rk0, rk1, rv0, rv1;
    float rm = 1.0f;
    {
        const ushort8* ksrc = (const ushort8*)(kb + (size_t)srow * QKV_LD + sc0);
        rk0 = ksrc[0]; rk1 = ksrc[1];
        const ushort8* vsrc = (const ushort8*)(vtb + (size_t)srow * SEQ + sc0);
        rv0 = vsrc[0]; rv1 = vsrc[1];
        if (t < 64) rm = mask[b * SEQ + t];
    }

    for (int kt = 0; kt < SEQ / 64; kt++) {
        // ---- store prefetched tile into LDS ----
        *(ushort8*)&Ks[sigrow * ASTR + sc0]     = rk0;
        *(ushort8*)&Ks[sigrow * ASTR + sc0 + 8] = rk1;
        *(ushort8*)&Vt[srow * ASTR + sc0]       = rv0;
        *(ushort8*)&Vt[srow * ASTR + sc0 + 8]   = rv1;
        if (t < 64) Ms[t] = -10000.0f * (1.0f - rm);
        __syncthreads();

        // ---- prefetch next tile (latency hidden under softmax compute) ----
        if (kt + 1 < SEQ / 64) {
            const int kn = (kt + 1) * 64;
            const ushort8* ksrc = (const ushort8*)(kb + (size_t)(kn + srow) * QKV_LD + sc0);
            rk0 = ksrc[0]; rk1 = ksrc[1];
            const ushort8* vsrc = (const ushort8*)(vtb + (size_t)srow * SEQ + kn + sc0);
            rv0 = vsrc[0]; rv1 = vsrc[1];
            if (t < 64) rm = mask[b * SEQ + kn + t];
        }

        // ---- S^T = K·Q^T over 4 slot-blocks (A = K, B = Q) ----
        f32x4 st[4];
        #pragma unroll
        for (int bi = 0; bi < 4; bi++) {
            const int krow = (bi * 16 + l16) * ASTR;
            short8 k0 = *(const short8*)&Ks[krow + quad * 8];
            short8 k1 = *(const short8*)&Ks[krow + 32 + quad * 8];
            f32x4 z = (f32x4){0.f, 0.f, 0.f, 0.f};
            z = __builtin_amdgcn_mfma_f32_16x16x32_bf16(k0, bq0, z, 0, 0, 0);
            st[bi] = __builtin_amdgcn_mfma_f32_16x16x32_bf16(k1, bq1, z, 0, 0, 0);
        }

        // ---- online softmax: lane owns query l16, keys quad*8..+7 per window ----
        float p[4][4];
        float mx = -3.0e38f;
        #pragma unroll
        for (int bi = 0; bi < 4; bi++) {
            #pragma unroll
            for (int r = 0; r < 4; r++) {
                float s = fmaf(st[bi][r], 0.125f,
                               Ms[((bi >> 1) << 5) + (quad << 3) + ((bi & 1) << 2) + r]);
                p[bi][r] = s;
                mx = fmaxf(mx, s);
            }
        }
        mx = fmaxf(mx, __shfl_xor(mx, 16, 64));
        mx = fmaxf(mx, __shfl_xor(mx, 32, 64));
        float m_new = fmaxf(m_st, mx);
        float alpha = __expf(m_st - m_new);
        m_st = m_new;
        float ls = 0.f;
        #pragma unroll
        for (int bi = 0; bi < 4; bi++) {
            #pragma unroll
            for (int r = 0; r < 4; r++) {
                p[bi][r] = __expf(p[bi][r] - m_new);
                ls += p[bi][r];
            }
        }
        ls += __shfl_xor(ls, 16, 64);
        ls += __shfl_xor(ls, 32, 64);
        l_st = l_st * alpha + ls;

        float ar[4];
        #pragma unroll
        for (int r = 0; r < 4; r++) ar[r] = __shfl(alpha, quad * 4 + r, 64);
        #pragma unroll
        for (int nt = 0; nt < 4; nt++)
            #pragma unroll
            for (int r = 0; r < 4; r++)
                o[nt][r] *= ar[r];

        short8 pf0, pf1;
        #pragma unroll
        for (int bsel = 0; bsel < 2; bsel++) {
            #pragma unroll
            for (int r = 0; r < 4; r++) {
                pf0[bsel * 4 + r] = (short)f2bf(p[bsel][r]);
                pf1[bsel * 4 + r] = (short)f2bf(p[2 + bsel][r]);
            }
        }

        // ---- PV: O += P · V  (B-frags from natural V^T rows) ----
        #pragma unroll
        for (int nt = 0; nt < 4; nt++) {
            const int vrow = (nt * 16 + l16) * ASTR;
            short8 v0 = *(const short8*)&Vt[vrow + quad * 8];
            short8 v1 = *(const short8*)&Vt[vrow + 32 + quad * 8];
            o[nt] = __builtin_amdgcn_mfma_f32_16x16x32_bf16(pf0, v0, o[nt], 0, 0, 0);
            o[nt] = __builtin_amdgcn_mfma_f32_16x16x32_bf16(pf1, v1, o[nt], 0, 0, 0);
        }
        __syncthreads();
    }

    float inv = 1.0f / l_st;
    float ir[4];
    #pragma unroll
    for (int r = 0; r < 4; r++) ir[r] = __shfl(inv, quad * 4 + r, 64);
    #pragma unroll
    for (int nt = 0; nt < 4; nt++) {
        #pragma unroll
        for (int r = 0; r < 4; r++) {
            int qi = q0 + wv * 16 + quad * 4 + r;
            out[(size_t)(b * SEQ + qi) * D_MODEL + h * HEAD_D + nt * 16 + l16] =
                f2bf(o[nt][r] * ir[r]);
        }
    }
}

// ---------------- LayerNorm over 768; optional second f32 input (split-K partial) --
__global__ __launch_bounds__(256) void ln_kernel(
    const float* __restrict__ in, const float* __restrict__ in2,
    const float* __restrict__ g, const float* __restrict__ be,
    float* __restrict__ outf, unsigned short* __restrict__ outb)
{
    const int row = blockIdx.x;
    const int t   = threadIdx.x;
    const float* rp  = in  + (size_t)row * D_MODEL;
    const float* rp2 = in2 ? in2 + (size_t)row * D_MODEL : nullptr;

    float vals[3];
    float s = 0.f, s2 = 0.f;
    #pragma unroll
    for (int i = 0; i < 3; i++) {
        float x = rp[t + i * 256];
        if (rp2) x += rp2[t + i * 256];
        vals[i] = x;
        s += x; s2 += x * x;
    }
    #pragma unroll
    for (int off = 32; off >= 1; off >>= 1) {
        s  += __shfl_xor(s,  off, 64);
        s2 += __shfl_xor(s2, off, 64);
    }
    __shared__ float rs[4], rs2[4];
    __shared__ float mu_s, rstd_s;
    const int wave = t >> 6, lane = t & 63;
    if (lane == 0) { rs[wave] = s; rs2[wave] = s2; }
    __syncthreads();
    if (t == 0) {
        float S1 = rs[0] + rs[1] + rs[2] + rs[3];
        float S2 = rs2[0] + rs2[1] + rs2[2] + rs2[3];
        float mu  = S1 * (1.0f / D_MODEL);
        float var = S2 * (1.0f / D_MODEL) - mu * mu;
        mu_s = mu;
        rstd_s = rsqrtf(var + 1e-12f);
    }
    __syncthreads();
    const float mu = mu_s, rstd = rstd_s;
    #pragma unroll
    for (int i = 0; i < 3; i++) {
        int c = t + i * 256;
        float o = g[c] * (vals[i] - mu) * rstd + be[c];
        if (outf) outf[(size_t)row * D_MODEL + c] = o;
        if (outb) outb[(size_t)row * D_MODEL + c] = f2bf(o);
    }
}

extern "C" void kernel_launch(void* const* d_in, const int* in_sizes, int n_in,
                              void* d_out, int out_size, void* d_ws, size_t ws_size,
                              hipStream_t stream)
{
    const float* x    = (const float*)d_in[0];
    const float* mask = (const float*)d_in[1];
    const float* Wq   = (const float*)d_in[2];
    const float* bq   = (const float*)d_in[3];
    const float* Wk   = (const float*)d_in[4];
    const float* bk   = (const float*)d_in[5];
    const float* Wv   = (const float*)d_in[6];
    const float* bv   = (const float*)d_in[7];
    const float* Wp   = (const float*)d_in[8];
    const float* bp   = (const float*)d_in[9];
    const float* g1   = (const float*)d_in[10];
    const float* be1  = (const float*)d_in[11];
    const float* W1   = (const float*)d_in[12];
    const float* bf1  = (const float*)d_in[13];
    const float* W2   = (const float*)d_in[14];
    const float* bf2  = (const float*)d_in[15];
    const float* g2   = (const float*)d_in[16];
    const float* be2  = (const float*)d_in[17];

    const int M = BATCH * SEQ;   // 4096

    // ---- workspace layout (bytes), ~83.4 MB total ----
    char* ws = (char*)d_ws;
    unsigned short* qkvb  = (unsigned short*)(ws + 0);         // [4096,2304] bf16
    unsigned short* ff1b  = (unsigned short*)(ws + 0);         // [4096,3072] bf16 (qkvb dead)
    unsigned short* xb    = (unsigned short*)(ws + 25165824);  // [4096,768] bf16 (live thru proj)
    unsigned short* hb    = (unsigned short*)(ws + 31457280);  // [4096,768] bf16
    unsigned short* x1b   = (unsigned short*)(ws + 31457280);  // alias (hb dead after proj)
    float*          y0    = (float*)(ws + 37748736);           // [4096,768] f32
    unsigned short* wqkvb = (unsigned short*)(ws + 50331648);  // [2304,768]
    unsigned short* wpb   = (unsigned short*)(ws + 53870592);  // [768,768]
    unsigned short* w1b   = (unsigned short*)(ws + 55050240);  // [3072,768]
    unsigned short* w2b   = (unsigned short*)(ws + 59768832);  // [768,3072]
    float*          bqkv  = (float*)(ws + 64487424);           // [2304]
    float*          p1    = (float*)(ws + 64496640);           // [4096,768] f32 split-K partial
    unsigned short* vTb   = (unsigned short*)(ws + 77079552);  // [24,64,2048] bf16 (6.3MB)

    dim3 blk(256);

    conv_fused<<<dim3(9985), blk, 0, stream>>>(
        x, Wq, Wk, Wv, Wp, W1, W2, bq, bk, bv,
        xb, wqkvb, wpb, w1b, w2b, bqkv);

    // fused QKV GEMM -> bf16
    gemm_bf16<<<dim3(QKV_LD / 128, M / 128, 1), blk, 0, stream>>>(
        xb, D_MODEL, wqkvb, D_MODEL, bqkv, nullptr, 0,
        nullptr, qkvb, nullptr, QKV_LD, M, QKV_LD, D_MODEL, 3);

    // one-shot V transpose
    vtrans<<<dim3(SEQ / 64, BATCH * N_HEAD), blk, 0, stream>>>(qkvb, vTb);

    // flash attention -> hb (bf16)
    attn_mfma<<<dim3(SEQ / 64, BATCH * N_HEAD), blk, 0, stream>>>(qkvb, vTb, mask, hb);

    // proj + residual, split-K x2: y0 (z=0: bias + xb) + p1 (z=1 raw)
    gemm_bf16<<<dim3(D_MODEL / 128, M / 128, 2), blk, 0, stream>>>(
        hb, D_MODEL, wpb, D_MODEL, bp, xb, D_MODEL,
        y0, nullptr, p1, D_MODEL, M, D_MODEL, D_MODEL, 1);

    // LN1 over (y0 + p1) -> x1b (bf16)
    ln_kernel<<<dim3(M), blk, 0, stream>>>(y0, p1, g1, be1, nullptr, x1b);

    // FFN1 + gelu -> ff1b (unsplit; gelu is nonlinear)
    gemm_bf16<<<dim3(D_FF / 128, M / 128, 1), blk, 0, stream>>>(
        x1b, D_MODEL, w1b, D_MODEL, bf1, nullptr, 0,
        nullptr, ff1b, nullptr, D_FF, M, D_FF, D_MODEL, 2);

    // FFN2 + residual, split-K x2: y0 (z=0: bias + x1b) + p1 (z=1 raw)
    gemm_bf16<<<dim3(D_MODEL / 128, M / 128, 2), blk, 0, stream>>>(
        ff1b, D_FF, w2b, D_FF, bf2, x1b, D_MODEL,
        y0, nullptr, p1, D_MODEL, M, D_MODEL, D_FF, 1);

    // LN2 over (y0 + p1) -> out (f32)
    ln_kernel<<<dim3(M), blk, 0, stream>>>(y0, p1, g2, be2, (float*)d_out, nullptr);
}